// Round 1
// baseline (358.955 us; speedup 1.0000x reference)
//
#include <hip/hip_runtime.h>

#define NTH 21
#define NBINS 84  // [0..20]=h_ac, [21..41]=h_au, [42..62]=h_ic, [63..83]=h_iu
#define EPSF 1e-10f

// ws layout: [0]: uint min_key (init 0xFFFFFFFF), [1]: uint max_key (init 0),
//            byte 8+: float partials[nb][NBINS]

static __device__ __forceinline__ unsigned fkey(float f) {
  unsigned u = __float_as_uint(f);
  return (u & 0x80000000u) ? ~u : (u | 0x80000000u);
}
static __device__ __forceinline__ float funkey(unsigned u) {
  return (u & 0x80000000u) ? __uint_as_float(u ^ 0x80000000u)
                           : __uint_as_float(~u);
}

__global__ void minmax_kernel(const float4* __restrict__ unc4, unsigned* __restrict__ mm,
                              int n4) {
  float lmin = 1e30f, lmax = -1e30f;
  int stride = gridDim.x * blockDim.x;
  for (int i = blockIdx.x * blockDim.x + threadIdx.x; i < n4; i += stride) {
    float4 v = unc4[i];
    lmin = fminf(lmin, fminf(fminf(v.x, v.y), fminf(v.z, v.w)));
    lmax = fmaxf(lmax, fmaxf(fmaxf(v.x, v.y), fmaxf(v.z, v.w)));
  }
  // wave (64-lane) reduce
  #pragma unroll
  for (int off = 32; off > 0; off >>= 1) {
    lmin = fminf(lmin, __shfl_down(lmin, off));
    lmax = fmaxf(lmax, __shfl_down(lmax, off));
  }
  __shared__ float smin[4], smax[4];  // 256 threads = 4 waves
  int wid = threadIdx.x >> 6;
  if ((threadIdx.x & 63) == 0) { smin[wid] = lmin; smax[wid] = lmax; }
  __syncthreads();
  if (threadIdx.x == 0) {
    float bmin = smin[0], bmax = smax[0];
    for (int w = 1; w < (blockDim.x >> 6); ++w) {
      bmin = fminf(bmin, smin[w]);
      bmax = fmaxf(bmax, smax[w]);
    }
    atomicMin(&mm[0], fkey(bmin));
    atomicMax(&mm[1], fkey(bmax));
  }
}

__global__ void hist_kernel(const float2* __restrict__ probs,
                            const int* __restrict__ labels,
                            const float* __restrict__ unc,
                            const unsigned* __restrict__ mm,
                            float* __restrict__ partials, int n) {
  __shared__ float lh[NBINS];
  for (int i = threadIdx.x; i < NBINS; i += blockDim.x) lh[i] = 0.f;
  float umin = funkey(mm[0]);
  float umax = funkey(mm[1]);
  float r = umax - umin;
  __syncthreads();
  int stride = gridDim.x * blockDim.x;
  for (int i = blockIdx.x * blockDim.x + threadIdx.x; i < n; i += stride) {
    float2 p = probs[i];
    float u = unc[i];
    int lab = labels[i];
    float conf = p.y;
    int pred = (p.y > p.x) ? 1 : 0;  // argmax: first index wins ties -> pred=1 only if strictly greater
    bool acc = (lab == pred);
    float t = tanhf(u);
    // bucket k = #{ j : u > umin + th_j * r }  (monotone thresholds)
    int k = 0;
    #pragma unroll
    for (int j = 0; j < NTH; ++j) {
      float thj = umin + ((float)j * 0.05f) * r;
      k += (u > thj) ? 1 : 0;
    }
    float w1 = acc ? conf : (1.0f - conf);
    int base = acc ? 0 : 42;
    atomicAdd(&lh[base + k], w1 * (1.0f - t));       // certain-side weight
    atomicAdd(&lh[base + 21 + k], w1 * t);           // uncertain-side weight
  }
  __syncthreads();
  for (int i = threadIdx.x; i < NBINS; i += blockDim.x)
    partials[(size_t)blockIdx.x * NBINS + i] = lh[i];
}

__global__ void finalize_kernel(const float* __restrict__ partials, int nb,
                                float* __restrict__ out) {
  __shared__ float h[NBINS];
  int t = threadIdx.x;
  if (t < NBINS) {
    float s = 0.f;
    for (int b = 0; b < nb; ++b) s += partials[(size_t)b * NBINS + t];
    h[t] = s;
  }
  __syncthreads();
  if (t == 0) {
    float tau = 0.f, tiu = 0.f;
    for (int i = 0; i < NTH; ++i) { tau += h[21 + i]; tiu += h[63 + i]; }
    float cac = 0.f, cic = 0.f, sau = tau, siu = tiu;
    float auc = 0.f, prev = 0.f, prev_th = 0.f;
    for (int i = 0; i < NTH; ++i) {
      cac += h[i];        // n_ac[i] = prefix sum (certain at threshold >= k)
      cic += h[42 + i];
      sau -= h[21 + i];   // n_au[i] = suffix sum (still uncertain)
      siu -= h[63 + i];
      float avu = (cac + siu) / (cac + sau + cic + siu + EPSF);
      float th = (float)i * 0.05f;
      if (i > 0) auc += 0.5f * (avu + prev) * (th - prev_th);
      prev = avu; prev_th = th;
    }
    out[0] = -logf(auc + EPSF);  // BETA = 1
    out[1] = auc;
  }
}

extern "C" void kernel_launch(void* const* d_in, const int* in_sizes, int n_in,
                              void* d_out, int out_size, void* d_ws, size_t ws_size,
                              hipStream_t stream) {
  const float* probs = (const float*)d_in[0];
  const int* labels = (const int*)d_in[1];
  const float* unc = (const float*)d_in[2];
  int n = in_sizes[2];  // N elements

  unsigned* mm = (unsigned*)d_ws;
  float* partials = (float*)((char*)d_ws + 8);

  // Choose #blocks for hist kernel, bounded by workspace size.
  int nb = 1024;
  while (nb > 1 && (size_t)(8 + (size_t)nb * NBINS * sizeof(float)) > ws_size) nb >>= 1;

  // init min key to 0xFFFFFFFF, max key to 0
  hipMemsetAsync(mm, 0xFF, 4, stream);
  hipMemsetAsync((char*)d_ws + 4, 0x00, 4, stream);

  minmax_kernel<<<1024, 256, 0, stream>>>((const float4*)unc, mm, n / 4);
  hist_kernel<<<nb, 256, 0, stream>>>((const float2*)probs, labels, unc, mm, partials, n);
  finalize_kernel<<<1, 128, 0, stream>>>(partials, nb, (float*)d_out);
}

// Round 2
// 130.576 us; speedup vs baseline: 2.7490x; 2.7490x over previous
//
#include <hip/hip_runtime.h>

#define NTH 21
#define NB_CAT 22            // bucket k in [0,21]; k=21 = "never certain"
#define NBINS (4 * NB_CAT)   // 88: [0..21]=ac, [22..43]=au, [44..65]=ic, [66..87]=iu
#define EPSF 1e-10f

// ws layout:
//   [0..7]    : uint min_key (init 0xFF), uint max_key (init 0x00)
//   [16..367] : float hist[88]          (written by reduce_kernel)
//   [384.. ]  : float partials[nb][88]  (written by hist_kernel)

static __device__ __forceinline__ unsigned fkey(float f) {
  unsigned u = __float_as_uint(f);
  return (u & 0x80000000u) ? ~u : (u | 0x80000000u);
}
static __device__ __forceinline__ float funkey(unsigned u) {
  return (u & 0x80000000u) ? __uint_as_float(u ^ 0x80000000u)
                           : __uint_as_float(~u);
}

__global__ void minmax_kernel(const float4* __restrict__ unc4, unsigned* __restrict__ mm,
                              int n4) {
  float lmin = 1e30f, lmax = -1e30f;
  int stride = gridDim.x * blockDim.x;
  for (int i = blockIdx.x * blockDim.x + threadIdx.x; i < n4; i += stride) {
    float4 v = unc4[i];
    lmin = fminf(lmin, fminf(fminf(v.x, v.y), fminf(v.z, v.w)));
    lmax = fmaxf(lmax, fmaxf(fmaxf(v.x, v.y), fmaxf(v.z, v.w)));
  }
  #pragma unroll
  for (int off = 32; off > 0; off >>= 1) {
    lmin = fminf(lmin, __shfl_down(lmin, off));
    lmax = fmaxf(lmax, __shfl_down(lmax, off));
  }
  __shared__ float smin[4], smax[4];
  int wid = threadIdx.x >> 6;
  if ((threadIdx.x & 63) == 0) { smin[wid] = lmin; smax[wid] = lmax; }
  __syncthreads();
  if (threadIdx.x == 0) {
    float bmin = smin[0], bmax = smax[0];
    for (int w = 1; w < (int)(blockDim.x >> 6); ++w) {
      bmin = fminf(bmin, smin[w]);
      bmax = fmaxf(bmax, smax[w]);
    }
    atomicMin(&mm[0], fkey(bmin));
    atomicMax(&mm[1], fkey(bmax));
  }
}

__global__ void __launch_bounds__(256) hist_kernel(
    const float2* __restrict__ probs,
    const int* __restrict__ labels,
    const float* __restrict__ unc,
    const unsigned* __restrict__ mm,
    float* __restrict__ partials, int n) {
  // per-wave private sub-histograms: 4 waves x 88 bins
  __shared__ float lh[4 * NBINS];
  for (int i = threadIdx.x; i < 4 * NBINS; i += blockDim.x) lh[i] = 0.f;
  float umin = funkey(mm[0]);
  float umax = funkey(mm[1]);
  float r = umax - umin;
  __syncthreads();

  float* wh = &lh[(threadIdx.x >> 6) * NBINS];
  int stride = gridDim.x * blockDim.x;
  for (int i = blockIdx.x * blockDim.x + threadIdx.x; i < n; i += stride) {
    float2 p = probs[i];
    float u = unc[i];
    int lab = labels[i];
    float conf = p.y;
    int pred = (p.y > p.x) ? 1 : 0;   // argmax: index 0 wins ties
    bool acc = (lab == pred);
    // tanh(u) = 1 - 2/(1+e^{2u}); u in [0,1) so no overflow concerns
    float e = __expf(2.0f * u);
    float t = 1.0f - 2.0f / (1.0f + e);
    // bucket k = #{ j : u > umin + (j*0.05)*r }  (matches reference thresholds)
    int k = 0;
    #pragma unroll
    for (int j = 0; j < NTH; ++j) {
      float thj = umin + ((float)j * 0.05f) * r;
      k += (u > thj) ? 1 : 0;
    }
    float w1 = acc ? conf : (1.0f - conf);
    int base = acc ? 0 : (2 * NB_CAT);
    atomicAdd(&wh[base + k], w1 * (1.0f - t));          // certain-side weight
    atomicAdd(&wh[base + NB_CAT + k], w1 * t);          // uncertain-side weight
  }
  __syncthreads();
  // merge 4 wave copies, write per-block partial
  for (int i = threadIdx.x; i < NBINS; i += blockDim.x) {
    float s = lh[i] + lh[NBINS + i] + lh[2 * NBINS + i] + lh[3 * NBINS + i];
    partials[(size_t)blockIdx.x * NBINS + i] = s;
  }
}

// one block per bin; 64 threads reduce over nb partials
__global__ void reduce_kernel(const float* __restrict__ partials, int nb,
                              float* __restrict__ hist) {
  int b = blockIdx.x;
  float s = 0.f;
  for (int i = threadIdx.x; i < nb; i += 64)
    s += partials[(size_t)i * NBINS + b];
  #pragma unroll
  for (int off = 32; off > 0; off >>= 1)
    s += __shfl_down(s, off);
  if (threadIdx.x == 0) hist[b] = s;
}

__global__ void finalize_kernel(const float* __restrict__ hist,
                                float* __restrict__ out) {
  __shared__ float h[NBINS];
  int t = threadIdx.x;
  if (t < NBINS) h[t] = hist[t];
  __syncthreads();
  if (t == 0) {
    const float* hac = &h[0];
    const float* hau = &h[NB_CAT];
    const float* hic = &h[2 * NB_CAT];
    const float* hiu = &h[3 * NB_CAT];
    float sau = 0.f, siu = 0.f;
    #pragma unroll
    for (int i = 0; i < NB_CAT; ++i) { sau += hau[i]; siu += hiu[i]; }
    float cac = 0.f, cic = 0.f;
    float auc = 0.f, prev = 0.f;
    #pragma unroll
    for (int i = 0; i < NTH; ++i) {
      cac += hac[i];   // n_ac[i]: elements certain by threshold i (k <= i)
      cic += hic[i];
      sau -= hau[i];   // n_au[i]: elements still uncertain (k > i), incl k=21
      siu -= hiu[i];
      float avu = (cac + siu) / (cac + sau + cic + siu + EPSF);
      if (i > 0) auc += 0.5f * (avu + prev) * 0.05f;
      prev = avu;
    }
    out[0] = -logf(auc + EPSF);  // BETA = 1
    out[1] = auc;
  }
}

extern "C" void kernel_launch(void* const* d_in, const int* in_sizes, int n_in,
                              void* d_out, int out_size, void* d_ws, size_t ws_size,
                              hipStream_t stream) {
  const float* probs = (const float*)d_in[0];
  const int* labels = (const int*)d_in[1];
  const float* unc = (const float*)d_in[2];
  int n = in_sizes[2];

  unsigned* mm = (unsigned*)d_ws;
  float* hist = (float*)((char*)d_ws + 16);
  float* partials = (float*)((char*)d_ws + 384);

  int nb = 512;
  while (nb > 1 && (size_t)(384 + (size_t)nb * NBINS * sizeof(float)) > ws_size) nb >>= 1;

  hipMemsetAsync(mm, 0xFF, 4, stream);            // min key = 0xFFFFFFFF
  hipMemsetAsync((char*)d_ws + 4, 0x00, 4, stream); // max key = 0

  minmax_kernel<<<1024, 256, 0, stream>>>((const float4*)unc, mm, n / 4);
  hist_kernel<<<nb, 256, 0, stream>>>((const float2*)probs, labels, unc, mm, partials, n);
  reduce_kernel<<<NBINS, 64, 0, stream>>>(partials, nb, hist);
  finalize_kernel<<<1, 128, 0, stream>>>(hist, (float*)d_out);
}

// Round 3
// 123.578 us; speedup vs baseline: 2.9047x; 1.0566x over previous
//
#include <hip/hip_runtime.h>

#define NTH 21
#define NROWS (2 * NTH + 2)      // 42 threshold accumulators + Snu + Sdu = 44
#define NBLK_MAIN 1024
#define THREADS_MAIN 256
#define EPSF 1e-10f

// ws layout:
//   [0]  : uint min_key          (init 0xFFFFFFFF)
//   [4]  : uint inv_max_key      (init 0xFFFFFFFF; stores ~fkey(max))
//   [64] : float partials[NROWS][NBLK_MAIN]   (transposed: row-major by accumulator)

static __device__ __forceinline__ unsigned fkey(float f) {
  unsigned u = __float_as_uint(f);
  return (u & 0x80000000u) ? ~u : (u | 0x80000000u);
}
static __device__ __forceinline__ float funkey(unsigned u) {
  return (u & 0x80000000u) ? __uint_as_float(u ^ 0x80000000u)
                           : __uint_as_float(~u);
}

__global__ void minmax_kernel(const float4* __restrict__ unc4, unsigned* __restrict__ mm,
                              int n4) {
  float lmin = 1e30f, lmax = -1e30f;
  int stride = gridDim.x * blockDim.x;
  for (int i = blockIdx.x * blockDim.x + threadIdx.x; i < n4; i += stride) {
    float4 v = unc4[i];
    lmin = fminf(lmin, fminf(fminf(v.x, v.y), fminf(v.z, v.w)));
    lmax = fmaxf(lmax, fmaxf(fmaxf(v.x, v.y), fmaxf(v.z, v.w)));
  }
  #pragma unroll
  for (int off = 32; off > 0; off >>= 1) {
    lmin = fminf(lmin, __shfl_down(lmin, off));
    lmax = fmaxf(lmax, __shfl_down(lmax, off));
  }
  __shared__ float smin[4], smax[4];
  int wid = threadIdx.x >> 6;
  if ((threadIdx.x & 63) == 0) { smin[wid] = lmin; smax[wid] = lmax; }
  __syncthreads();
  if (threadIdx.x == 0) {
    float bmin = smin[0], bmax = smax[0];
    for (int w = 1; w < (int)(blockDim.x >> 6); ++w) {
      bmin = fminf(bmin, smin[w]);
      bmax = fmaxf(bmax, smax[w]);
    }
    atomicMin(&mm[0], fkey(bmin));
    atomicMin(&mm[1], ~fkey(bmax));   // inverted key: atomicMin == max
  }
}

__global__ void __launch_bounds__(THREADS_MAIN) main_kernel(
    const float4* __restrict__ probs4,
    const int4* __restrict__ labels4,
    const float4* __restrict__ unc4,
    const unsigned* __restrict__ mm,
    float* __restrict__ partials, int n4) {
  // wave-uniform min/max -> scalar regs -> scalar thresholds
  unsigned kmin = __builtin_amdgcn_readfirstlane(mm[0]);
  unsigned kmax = __builtin_amdgcn_readfirstlane(~mm[1]);
  float umin = funkey(kmin);
  float umax = funkey(kmax);
  float r = umax - umin;
  float th[NTH];
  #pragma unroll
  for (int j = 0; j < NTH; ++j) th[j] = umin + ((float)j * 0.05f) * r;

  float accn[NTH], accd[NTH];
  #pragma unroll
  for (int j = 0; j < NTH; ++j) { accn[j] = 0.f; accd[j] = 0.f; }
  float Snu = 0.f, Sdu = 0.f;

  int tid = blockIdx.x * THREADS_MAIN + threadIdx.x;
  int stride = NBLK_MAIN * THREADS_MAIN;
  for (int i4 = tid; i4 < n4; i4 += stride) {
    float4 u4 = unc4[i4];
    float4 pA = probs4[(size_t)i4 * 2];
    float4 pB = probs4[(size_t)i4 * 2 + 1];
    int4 lb = labels4[i4];
    float us[4] = {u4.x, u4.y, u4.z, u4.w};
    float pxs[4] = {pA.x, pA.z, pB.x, pB.z};
    float pys[4] = {pA.y, pA.w, pB.y, pB.w};
    int labs[4] = {lb.x, lb.y, lb.z, lb.w};
    #pragma unroll
    for (int e = 0; e < 4; ++e) {
      float u = us[e];
      float conf = pys[e];
      int pred = (pys[e] > pxs[e]) ? 1 : 0;
      bool accb = (labs[e] == pred);
      float ex = __expf(2.0f * u);
      float t = 1.0f - 2.0f / (1.0f + ex);     // tanh(u)
      float w1 = accb ? conf : (1.0f - conf);
      float du_ = w1 * t;                       // uncertain-side weight
      float dc  = w1 - du_;                     // certain-side weight
      float dd  = dc - du_;                     // den delta when certain
      float dn  = accb ? dc : -du_;             // num delta when certain
      float nu  = accb ? 0.f : du_;             // num base (uncertain)
      Snu += nu;
      Sdu += du_;
      #pragma unroll
      for (int j = 0; j < NTH; ++j) {
        float cf = (u <= th[j]) ? 1.0f : 0.0f;
        accn[j] += cf * dn;
        accd[j] += cf * dd;
      }
    }
  }

  // wave reduce 44 values, cross-wave via LDS, write transposed partials
  __shared__ float lds[4][NROWS];
  int lane = threadIdx.x & 63, wv = threadIdx.x >> 6;
  #pragma unroll
  for (int v = 0; v < NTH; ++v) {
    float x = accn[v];
    float y = accd[v];
    #pragma unroll
    for (int off = 32; off > 0; off >>= 1) {
      x += __shfl_down(x, off);
      y += __shfl_down(y, off);
    }
    if (lane == 0) { lds[wv][v] = x; lds[wv][NTH + v] = y; }
  }
  {
    float x = Snu, y = Sdu;
    #pragma unroll
    for (int off = 32; off > 0; off >>= 1) {
      x += __shfl_down(x, off);
      y += __shfl_down(y, off);
    }
    if (lane == 0) { lds[wv][2 * NTH] = x; lds[wv][2 * NTH + 1] = y; }
  }
  __syncthreads();
  int t = threadIdx.x;
  if (t < NROWS) {
    float s = lds[0][t] + lds[1][t] + lds[2][t] + lds[3][t];
    partials[(size_t)t * NBLK_MAIN + blockIdx.x] = s;
  }
}

// one block: 44 rows x 16 chunks = 704 threads; each sums 64 floats (16 float4)
__global__ void final_kernel(const float* __restrict__ partials,
                             float* __restrict__ out) {
  __shared__ float lds[NROWS][16];
  __shared__ float h[NROWS];
  int t = threadIdx.x;
  if (t < NROWS * 16) {
    int row = t >> 4, ch = t & 15;
    const float4* p4 = (const float4*)(partials + (size_t)row * NBLK_MAIN + ch * 64);
    float s = 0.f;
    #pragma unroll
    for (int m = 0; m < 16; ++m) {
      float4 v = p4[m];
      s += (v.x + v.y) + (v.z + v.w);
    }
    lds[row][ch] = s;
  }
  __syncthreads();
  if (t < NROWS) {
    float s = 0.f;
    #pragma unroll
    for (int c = 0; c < 16; ++c) s += lds[t][c];
    h[t] = s;
  }
  __syncthreads();
  if (t == 0) {
    float Snu = h[2 * NTH], Sdu = h[2 * NTH + 1];
    float auc = 0.f, prev = 0.f;
    #pragma unroll
    for (int j = 0; j < NTH; ++j) {
      float num = Snu + h[j];
      float den = Sdu + h[NTH + j];
      float avu = num / (den + EPSF);
      if (j > 0) auc += 0.5f * (avu + prev) * 0.05f;
      prev = avu;
    }
    out[0] = -logf(auc + EPSF);   // BETA = 1
    out[1] = auc;
  }
}

extern "C" void kernel_launch(void* const* d_in, const int* in_sizes, int n_in,
                              void* d_out, int out_size, void* d_ws, size_t ws_size,
                              hipStream_t stream) {
  const float* probs = (const float*)d_in[0];
  const int* labels = (const int*)d_in[1];
  const float* unc = (const float*)d_in[2];
  int n = in_sizes[2];

  unsigned* mm = (unsigned*)d_ws;
  float* partials = (float*)((char*)d_ws + 64);

  // both keys init to 0xFFFFFFFF (min key, and inverted max key)
  hipMemsetAsync(mm, 0xFF, 8, stream);

  minmax_kernel<<<1024, 256, 0, stream>>>((const float4*)unc, mm, n / 4);
  main_kernel<<<NBLK_MAIN, THREADS_MAIN, 0, stream>>>(
      (const float4*)probs, (const int4*)labels, (const float4*)unc, mm,
      partials, n / 4);
  final_kernel<<<1, NROWS * 16, 0, stream>>>(partials, (float*)d_out);
}